// Round 9
// baseline (150.146 us; speedup 1.0000x reference)
//
#include <hip/hip_runtime.h>

#define NB 4
#define NC 64
#define NCH 32
#define NPIX 131072   // 32*64*64

// ---- workspace float offsets (small region, both paths) ----
#define O_SUME 0
#define O_CTX  8
#define O_QL   136
#define O_SCA  264
#define O_SA   272
#define O_AVGX 528
#define O_K    656
// fallback-path transposed weights
#define O_WT1  1024
#define WT1_S  68
#define O_WT3  6144
#define O_WT5  8192
// ---- fast-path byte offsets ----
#define AF1_OFF 4096u        // [5][2][64][8] u16 = 10240 B  (vr0,vr1,ql0,ql1,qr)
#define AF3_OFF 14336u       // [2][2][64][8] u16 = 4096 B   (vl0,vl1)
#define AF5_OFF 18432u       // [4][2][64][8] u16 = 8192 B   (wres)
#define PB_OFF  32768u       // partials [NB][65][NTBLK] f32 = 2129920 B
#define PB_F    8192         // float index of PB_OFF
#define NTBLK   2048         // k_Tp1 grid.x
#define XT_OFF  2162688u     // x_t bf16: 4*131072*64*2 = 67108864 B
#define WS_NEED 69271552u

typedef short bf16x8 __attribute__((ext_vector_type(8)));
typedef float f32x4  __attribute__((ext_vector_type(4)));
typedef unsigned short u16x8 __attribute__((ext_vector_type(8)));

__device__ __forceinline__ float wave_sum64(float v) {
#pragma unroll
    for (int m = 32; m; m >>= 1) v += __shfl_xor(v, m, 64);
    return v;
}
__device__ __forceinline__ float gsum16(float v) {   // reduce over col bits (0..3)
#pragma unroll
    for (int m = 8; m; m >>= 1) v += __shfl_xor(v, m, 64);
    return v;
}
__device__ __forceinline__ unsigned short f2bf(float f) {
    unsigned u = __float_as_uint(f);
    u += 0x7FFFu + ((u >> 16) & 1u);
    return (unsigned short)(u >> 16);
}

// ================= FAST PATH =================

// prep: pack bf16 A-fragments for 16x16x32 MFMA (1 block, runs first).
__global__ __launch_bounds__(256) void k_prepf(
    const float* __restrict__ wqr, const float* __restrict__ wvr,
    const float* __restrict__ wql, const float* __restrict__ wvl,
    const float* __restrict__ wres, float* __restrict__ ws) {
    unsigned short* af1 = (unsigned short*)((char*)ws + AF1_OFF);
    unsigned short* af3 = (unsigned short*)((char*)ws + AF3_OFF);
    unsigned short* af5 = (unsigned short*)((char*)ws + AF5_OFF);
    for (int idx = threadIdx.x; idx < 5 * 2 * 64 * 8; idx += 256) {
        int j = idx & 7, lane = (idx >> 3) & 63, s = (idx >> 9) & 1, t = idx >> 10;
        int row = lane & 15, kg = lane >> 4, c = s * 32 + kg * 8 + j;
        float v;
        if (t < 2)      v = wvr[(t * 16 + row) * NC + c];
        else if (t < 4) v = wql[((t - 2) * 16 + row) * NC + c];
        else            v = (row == 0) ? wqr[c] : 0.f;
        af1[idx] = f2bf(v);
    }
    for (int idx = threadIdx.x; idx < 2 * 2 * 64 * 8; idx += 256) {
        int j = idx & 7, lane = (idx >> 3) & 63, s = (idx >> 9) & 1, t = idx >> 10;
        int row = lane & 15, kg = lane >> 4, c = s * 32 + kg * 8 + j;
        af3[idx] = f2bf(wvl[(t * 16 + row) * NC + c]);
    }
    for (int idx = threadIdx.x; idx < 4 * 2 * 64 * 8; idx += 256) {
        int j = idx & 7, lane = (idx >> 3) & 63, s = (idx >> 9) & 1, t = idx >> 10;
        int row = lane & 15, kg = lane >> 4, c = s * 32 + kg * 8 + j;
        af5[idx] = f2bf(wres[(t * 16 + row) * NC + c]);
    }
}

// Tp1: transpose x tile -> xt (bf16) AND p1 MFMA reductions, B-fragments
// built by in-register wave shuffle of the just-transposed data.
__global__ __launch_bounds__(256) void k_Tp1(
    const float* __restrict__ x, unsigned short* __restrict__ xt,
    const float* __restrict__ wsro, float* __restrict__ ws) {
    const int b = blockIdx.y;
    const int n0 = blockIdx.x * 64;
    const int t = threadIdx.x;
    __shared__ float lds[64 * 65];
    __shared__ float red[65];     // 0..31 ctx, 32..63 ql, 64 sume
    for (int i = t; i < 65; i += 256) red[i] = 0.f;

    // ---- load + LDS transpose (proven k_T pattern) ----
    const int c = t >> 2, q = t & 3;
    const float* src = x + (size_t)(b * NC + c) * NPIX + n0;
#pragma unroll
    for (int k = 0; k < 4; ++k) {
        float4 v = *(const float4*)(src + q * 4 + k * 16);
        lds[c * 65 + q * 4 + k * 16 + 0] = v.x;
        lds[c * 65 + q * 4 + k * 16 + 1] = v.y;
        lds[c * 65 + q * 4 + k * 16 + 2] = v.z;
        lds[c * 65 + q * 4 + k * 16 + 3] = v.w;
    }
    __syncthreads();

    // ---- xt write (proven k_T pattern); o0/o1 stay live in registers ----
    const int nl = t >> 2, cq = t & 3;
    u16x8 o0, o1;
#pragma unroll
    for (int i = 0; i < 8; ++i) o0[i] = f2bf(lds[(cq * 16 + i) * 65 + nl]);
#pragma unroll
    for (int i = 0; i < 8; ++i) o1[i] = f2bf(lds[(cq * 16 + 8 + i) * 65 + nl]);
    {
        unsigned short* dst = xt + ((size_t)b * NPIX + n0 + nl) * NC + cq * 16;
        *(u16x8*)(dst) = o0;
        *(u16x8*)(dst + 8) = o1;
    }

    // ---- B-fragments via in-register wave shuffle ----
    // lane(col,kg) needs: B0 = (kg&1 ? o1 : o0) of lane col*4+(kg>>1)
    //                     B1 = same from lane col*4+2+(kg>>1)
    const int lane = t & 63;
    const int col = lane & 15, kg = lane >> 4;
    const int s0 = (col << 2) + (kg >> 1);
    const int s1 = s0 + 2;
    int b0w[4], b1w[4];
    const int* p0 = (const int*)&o0;
    const int* p1 = (const int*)&o1;
#pragma unroll
    for (int i = 0; i < 4; ++i) {
        int v0 = __shfl(p0[i], s0, 64);
        int v1 = __shfl(p1[i], s0, 64);
        b0w[i] = (kg & 1) ? v1 : v0;
        int w0 = __shfl(p0[i], s1, 64);
        int w1 = __shfl(p1[i], s1, 64);
        b1w[i] = (kg & 1) ? w1 : w0;
    }
    bf16x8 B0 = *(bf16x8*)b0w;
    bf16x8 B1 = *(bf16x8*)b1w;

    // ---- A-fragments from packed af1 (L2-hot) ----
    const unsigned short* af1 = (const unsigned short*)((const char*)wsro + AF1_OFF);
    bf16x8 A[5][2];
#pragma unroll
    for (int tt = 0; tt < 5; ++tt)
#pragma unroll
        for (int s = 0; s < 2; ++s)
            A[tt][s] = *(const bf16x8*)(af1 + ((tt * 2 + s) * 64 + lane) * 8);

    // ---- p1 math (verbatim from proven k_p1, single tile) ----
    f32x4 c6 = {0.f, 0.f, 0.f, 0.f};
    c6 = __builtin_amdgcn_mfma_f32_16x16x32_bf16(A[4][0], B0, c6, 0, 0, 0);
    c6 = __builtin_amdgcn_mfma_f32_16x16x32_bf16(A[4][1], B1, c6, 0, 0, 0);
    float e = __expf(fmaxf(c6[0], 0.f));
    e = __shfl(e, col, 64);              // row-0 value for pixel col
    float acc_e = wave_sum64(e) * 0.25f; // kg duplicates corrected
    if (lane == 0) atomicAdd(&red[64], acc_e);

    f32x4 c0 = {0.f, 0.f, 0.f, 0.f}, c1 = {0.f, 0.f, 0.f, 0.f};
    c0 = __builtin_amdgcn_mfma_f32_16x16x32_bf16(A[0][0], B0, c0, 0, 0, 0);
    c0 = __builtin_amdgcn_mfma_f32_16x16x32_bf16(A[0][1], B1, c0, 0, 0, 0);
    c1 = __builtin_amdgcn_mfma_f32_16x16x32_bf16(A[1][0], B0, c1, 0, 0, 0);
    c1 = __builtin_amdgcn_mfma_f32_16x16x32_bf16(A[1][1], B1, c1, 0, 0, 0);
    float ctx[8];
#pragma unroll
    for (int r = 0; r < 4; ++r) {
        ctx[r]     = fmaxf(c0[r], 0.f) * e;
        ctx[4 + r] = fmaxf(c1[r], 0.f) * e;
    }
    c0 = f32x4{0.f, 0.f, 0.f, 0.f}; c1 = f32x4{0.f, 0.f, 0.f, 0.f};
    c0 = __builtin_amdgcn_mfma_f32_16x16x32_bf16(A[2][0], B0, c0, 0, 0, 0);
    c0 = __builtin_amdgcn_mfma_f32_16x16x32_bf16(A[2][1], B1, c0, 0, 0, 0);
    c1 = __builtin_amdgcn_mfma_f32_16x16x32_bf16(A[3][0], B0, c1, 0, 0, 0);
    c1 = __builtin_amdgcn_mfma_f32_16x16x32_bf16(A[3][1], B1, c1, 0, 0, 0);
    float qla[8];
#pragma unroll
    for (int r = 0; r < 4; ++r) {
        qla[r]     = fmaxf(c0[r], 0.f);
        qla[4 + r] = fmaxf(c1[r], 0.f);
    }
#pragma unroll
    for (int i = 0; i < 8; ++i) {
        float v = gsum16(ctx[i]);
        float qv = gsum16(qla[i]);
        if (col == 0) {
            int ch = (i >> 2) * 16 + kg * 4 + (i & 3);
            atomicAdd(&red[ch], v);       // LDS atomics, block-scope
            atomicAdd(&red[32 + ch], qv);
        }
    }
    __syncthreads();
    float* pb = ws + PB_F;
    if (t < 65)
        pb[((size_t)b * 65 + t) * NTBLK + blockIdx.x] = red[t];
}

// red: parallel partial reduction -> SUME/CTX/QL; zero SCA. grid (65, NB).
__global__ __launch_bounds__(256) void k_red(float* __restrict__ ws) {
    const int slot = blockIdx.x;   // 0..64
    const int b = blockIdx.y;
    const float* p = ws + PB_F + ((size_t)b * 65 + slot) * NTBLK;
    float s = 0.f;
    for (int i = threadIdx.x; i < NTBLK; i += 256) s += p[i];
    s = wave_sum64(s);
    __shared__ float r4[4];
    if ((threadIdx.x & 63) == 0) r4[threadIdx.x >> 6] = s;
    __syncthreads();
    if (threadIdx.x == 0) {
        float tot = r4[0] + r4[1] + r4[2] + r4[3];
        if (slot < 32)      ws[O_CTX + b * NCH + slot] = tot;
        else if (slot < 64) ws[O_QL + b * NCH + (slot - 32)] = tot;
        else { ws[O_SUME + b] = tot; ws[O_SCA + b] = 0.f; }
    }
}

#define TPW 8
// p3 (MFMA): S_ca = sum_n sigmoid(sum_ch avgx[ch]*relu(wvl x)); 1 atomic/block
__global__ __launch_bounds__(256) void k_p3v(
    const unsigned short* __restrict__ xt, float* __restrict__ ws) {
    const int b = blockIdx.y;
    const int lane = threadIdx.x & 63;
    const int wid = blockIdx.x * 4 + (threadIdx.x >> 6);
    const int col = lane & 15, kg = lane >> 4;
    const unsigned short* af3 = (const unsigned short*)((const char*)ws + AF3_OFF);

    __shared__ float red;
    if (threadIdx.x == 0) red = 0.f;
    __syncthreads();

    bf16x8 A[2][2];
#pragma unroll
    for (int t = 0; t < 2; ++t)
#pragma unroll
        for (int s = 0; s < 2; ++s)
            A[t][s] = *(const bf16x8*)(af3 + ((t * 2 + s) * 64 + lane) * 8);
    float ax0[4], ax1[4];
#pragma unroll
    for (int r = 0; r < 4; ++r) {
        ax0[r] = ws[O_AVGX + b * NCH + kg * 4 + r];
        ax1[r] = ws[O_AVGX + b * NCH + 16 + kg * 4 + r];
    }

    float acc = 0.f;
    for (int it = 0; it < TPW; ++it) {
        const int n0 = (wid * TPW + it) * 16;
        const unsigned short* xr = xt + ((size_t)b * NPIX + n0 + col) * NC + kg * 8;
        bf16x8 B0 = *(const bf16x8*)(xr);
        bf16x8 B1 = *(const bf16x8*)(xr + 32);
        f32x4 c0 = {0.f, 0.f, 0.f, 0.f}, c1 = {0.f, 0.f, 0.f, 0.f};
        c0 = __builtin_amdgcn_mfma_f32_16x16x32_bf16(A[0][0], B0, c0, 0, 0, 0);
        c0 = __builtin_amdgcn_mfma_f32_16x16x32_bf16(A[0][1], B1, c0, 0, 0, 0);
        c1 = __builtin_amdgcn_mfma_f32_16x16x32_bf16(A[1][0], B0, c1, 0, 0, 0);
        c1 = __builtin_amdgcn_mfma_f32_16x16x32_bf16(A[1][1], B1, c1, 0, 0, 0);
        float sp = 0.f;
#pragma unroll
        for (int r = 0; r < 4; ++r) {
            sp = fmaf(ax0[r], fmaxf(c0[r], 0.f), sp);
            sp = fmaf(ax1[r], fmaxf(c1[r], 0.f), sp);
        }
        sp += __shfl_xor(sp, 16, 64);     // reduce over kg
        sp += __shfl_xor(sp, 32, 64);
        acc += 1.f / (1.f + __expf(-sp)); // every pixel counted 4x (kg copies)
    }
    acc = wave_sum64(acc) * 0.25f;
    if (lane == 0) atomicAdd(&red, acc);
    __syncthreads();
    if (threadIdx.x == 0) atomicAdd(&ws[O_SCA + b], red);
}

// p5: SK gating (fused) then out = K[b,o] + relu(wres x) via SWAPPED MFMA:
// D[px][o] -> each lane's 4 regs are 4 consecutive n -> float4 stores.
__global__ __launch_bounds__(256) void k_p5(
    const unsigned short* __restrict__ xt, const float* __restrict__ ws,
    const float* __restrict__ wsk1, const float* __restrict__ wsk2,
    float* __restrict__ out) {
    const int b = blockIdx.y;
    const int tid = threadIdx.x;
    const int lane = tid & 63;
    const int wid = blockIdx.x * 4 + (tid >> 6);
    const int col = lane & 15, kg = lane >> 4;
    const unsigned short* af5 = (const unsigned short*)((const char*)ws + AF5_OFF);

    __shared__ float u_s[NC];
    __shared__ float a1_s[NCH];
    __shared__ float K_s[NC];

    // ---- fused pass4 (redundant per block) ----
    const float invn = 1.f / (float)NPIX;
    if (tid < NC) {
        float sca = ws[O_SCA + b];
        float sa = ws[O_SA + b * NC + tid];
        u_s[tid] = fmaf(sa, sca * invn, invn);
    }
    __syncthreads();
    if (tid < NCH) {
        float s = 0.f;
#pragma unroll
        for (int c = 0; c < NC; ++c) s = fmaf(wsk1[tid * NC + c], u_s[c], s);
        a1_s[tid] = fmaxf(s, 0.f);
    }
    __syncthreads();
    if (tid < NC) {
        float s2 = 0.f;
#pragma unroll
        for (int ch = 0; ch < NCH; ++ch) s2 = fmaf(wsk2[tid * NCH + ch], a1_s[ch], s2);
        s2 = fmaxf(s2, 0.f);
        float mx = s2;
#pragma unroll
        for (int m = 32; m; m >>= 1) mx = fmaxf(mx, __shfl_xor(mx, m, 64));
        float e = __expf(s2 - mx);
        float sm = e;
#pragma unroll
        for (int m = 32; m; m >>= 1) sm += __shfl_xor(sm, m, 64);
        float a = e / sm;
        float sca = ws[O_SCA + b];
        float sa = ws[O_SA + b * NC + tid];
        K_s[tid] = fmaf(a, sa * sca, 1.f - a);
    }
    __syncthreads();

    bf16x8 A[4][2];
#pragma unroll
    for (int t = 0; t < 4; ++t)
#pragma unroll
        for (int s = 0; s < 2; ++s)
            A[t][s] = *(const bf16x8*)(af5 + ((t * 2 + s) * 64 + lane) * 8);
    float kvc[4];
#pragma unroll
    for (int t = 0; t < 4; ++t) kvc[t] = K_s[t * 16 + col];

    for (int it = 0; it < TPW; ++it) {
        const int n0 = (wid * TPW + it) * 16;
        const unsigned short* xr = xt + ((size_t)b * NPIX + n0 + col) * NC + kg * 8;
        bf16x8 B0 = *(const bf16x8*)(xr);
        bf16x8 B1 = *(const bf16x8*)(xr + 32);
#pragma unroll
        for (int t = 0; t < 4; ++t) {
            f32x4 cc = {0.f, 0.f, 0.f, 0.f};
            cc = __builtin_amdgcn_mfma_f32_16x16x32_bf16(B0, A[t][0], cc, 0, 0, 0);
            cc = __builtin_amdgcn_mfma_f32_16x16x32_bf16(B1, A[t][1], cc, 0, 0, 0);
            float4 r;
            r.x = kvc[t] + fmaxf(cc[0], 0.f);
            r.y = kvc[t] + fmaxf(cc[1], 0.f);
            r.z = kvc[t] + fmaxf(cc[2], 0.f);
            r.w = kvc[t] + fmaxf(cc[3], 0.f);
            *(float4*)(out + ((size_t)(b * NC + t * 16 + col)) * NPIX + n0 + kg * 4) = r;
        }
    }
}

// ================= shared small kernel (p2) =================
__global__ __launch_bounds__(256) void k_pass2(
    const float* __restrict__ wup, float* __restrict__ ws) {
    const int b = threadIdx.x >> 6;
    const int lane = threadIdx.x & 63;
    __shared__ float ln_s[NB][NCH];
    float se = ws[O_SUME + b];
    float ctx = (lane < NCH) ? (ws[O_CTX + b * NCH + lane] / se) : 0.f;
    float v = ctx, v2 = ctx * ctx;
#pragma unroll
    for (int m = 16; m; m >>= 1) { v += __shfl_xor(v, m, 64); v2 += __shfl_xor(v2, m, 64); }
    float mu = v / (float)NCH;
    float var = v2 / (float)NCH - mu * mu;
    float lnv = (ctx - mu) * rsqrtf(var + 1e-5f);
    if (lane < NCH) ln_s[b][lane] = lnv;
    __syncthreads();
    float s = 0.f;
#pragma unroll
    for (int ch = 0; ch < NCH; ++ch) s = fmaf(wup[lane * NCH + ch], ln_s[b][ch], s);
    ws[O_SA + b * NC + lane] = fminf(fmaxf((s + 3.f) * (1.f / 6.f), 0.f), 1.f);
    if (lane < NCH) {
        float l = ws[O_QL + b * NCH + lane] * (1.f / (float)NPIX);
        float mx = l;
#pragma unroll
        for (int m = 16; m; m >>= 1) mx = fmaxf(mx, __shfl_xor(mx, m, 64));
        float e = __expf(l - mx);
        float sm = e;
#pragma unroll
        for (int m = 16; m; m >>= 1) sm += __shfl_xor(sm, m, 64);
        ws[O_AVGX + b * NCH + lane] = e / sm;
    }
}

// ================= FALLBACK PATH (R2, passing) =================
__global__ __launch_bounds__(256) void k_prep(
    const float* __restrict__ wqr, const float* __restrict__ wvr,
    const float* __restrict__ wql, const float* __restrict__ wvl,
    const float* __restrict__ wres, float* __restrict__ ws) {
    for (int i = threadIdx.x; i < NC * WT1_S; i += 256) {
        int c = i / WT1_S, j = i % WT1_S;
        float v = 0.f;
        if (j == 0)       v = wqr[c];
        else if (j <= 32) v = wvr[(j - 1) * NC + c];
        else if (j <= 64) v = wql[(j - 33) * NC + c];
        ws[O_WT1 + i] = v;
    }
    for (int i = threadIdx.x; i < NC * NCH; i += 256) {
        int c = i / NCH, ch = i % NCH;
        ws[O_WT3 + i] = wvl[ch * NC + c];
    }
    for (int i = threadIdx.x; i < NC * NC; i += 256) {
        int c = i / NC, o = i % NC;
        ws[O_WT5 + i] = wres[o * NC + c];
    }
}

__global__ __launch_bounds__(256) void k_pass1(
    const float* __restrict__ x, float* __restrict__ ws) {
    const int b = blockIdx.y;
    const float* xb = x + (size_t)b * NC * NPIX;
    __shared__ float wlds[NC * WT1_S];
    __shared__ float red[1 + 2 * NCH];
    for (int i = threadIdx.x; i < NC * WT1_S; i += 256) wlds[i] = ws[O_WT1 + i];
    for (int i = threadIdx.x; i < 1 + 2 * NCH; i += 256) red[i] = 0.f;
    __syncthreads();
    const int n2 = blockIdx.x * 256 + threadIdx.x;
    float dqr0 = 0.f, dqr1 = 0.f;
    float dv[NCH][2], dq[NCH][2];
#pragma unroll
    for (int i = 0; i < NCH; ++i) { dv[i][0] = dv[i][1] = 0.f; dq[i][0] = dq[i][1] = 0.f; }
    for (int c = 0; c < NC; ++c) {
        const float2 xv = *(const float2*)(xb + (size_t)c * NPIX + 2 * n2);
        const float* wr = wlds + c * WT1_S;
        dqr0 = fmaf(wr[0], xv.x, dqr0);
        dqr1 = fmaf(wr[0], xv.y, dqr1);
#pragma unroll
        for (int ch = 0; ch < NCH; ++ch) {
            const float wv = wr[1 + ch], wq = wr[33 + ch];
            dv[ch][0] = fmaf(wv, xv.x, dv[ch][0]);
            dv[ch][1] = fmaf(wv, xv.y, dv[ch][1]);
            dq[ch][0] = fmaf(wq, xv.x, dq[ch][0]);
            dq[ch][1] = fmaf(wq, xv.y, dq[ch][1]);
        }
    }
    const float e0 = __expf(fmaxf(dqr0, 0.f));
    const float e1 = __expf(fmaxf(dqr1, 0.f));
    float acc_e = wave_sum64(e0 + e1);
    if ((threadIdx.x & 63) == 0) atomicAdd(&red[0], acc_e);
#pragma unroll
    for (int ch = 0; ch < NCH; ++ch) {
        float v = wave_sum64(fmaxf(dv[ch][0], 0.f) * e0 + fmaxf(dv[ch][1], 0.f) * e1);
        float q = wave_sum64(fmaxf(dq[ch][0], 0.f) + fmaxf(dq[ch][1], 0.f));
        if ((threadIdx.x & 63) == 0) { atomicAdd(&red[1 + ch], v); atomicAdd(&red[1 + NCH + ch], q); }
    }
    __syncthreads();
    if (threadIdx.x == 0) atomicAdd(&ws[O_SUME + b], red[0]);
    if (threadIdx.x < NCH) {
        atomicAdd(&ws[O_CTX + b * NCH + threadIdx.x], red[1 + threadIdx.x]);
        atomicAdd(&ws[O_QL  + b * NCH + threadIdx.x], red[1 + NCH + threadIdx.x]);
    }
}

__global__ __launch_bounds__(256) void k_pass3(
    const float* __restrict__ x, float* __restrict__ ws) {
    const int b = blockIdx.y;
    const float* xb = x + (size_t)b * NC * NPIX;
    __shared__ float wlds[NC * NCH];
    __shared__ float red;
    for (int i = threadIdx.x; i < NC * NCH; i += 256) wlds[i] = ws[O_WT3 + i];
    if (threadIdx.x == 0) red = 0.f;
    __syncthreads();
    const int n2 = blockIdx.x * 256 + threadIdx.x;
    float dv[NCH][2];
#pragma unroll
    for (int i = 0; i < NCH; ++i) dv[i][0] = dv[i][1] = 0.f;
    for (int c = 0; c < NC; ++c) {
        const float2 xv = *(const float2*)(xb + (size_t)c * NPIX + 2 * n2);
        const float* wr = wlds + c * NCH;
#pragma unroll
        for (int ch = 0; ch < NCH; ++ch) {
            dv[ch][0] = fmaf(wr[ch], xv.x, dv[ch][0]);
            dv[ch][1] = fmaf(wr[ch], xv.y, dv[ch][1]);
        }
    }
    float s0 = 0.f, s1 = 0.f;
#pragma unroll
    for (int ch = 0; ch < NCH; ++ch) {
        const float ax = ws[O_AVGX + b * NCH + ch];
        s0 = fmaf(ax, fmaxf(dv[ch][0], 0.f), s0);
        s1 = fmaf(ax, fmaxf(dv[ch][1], 0.f), s1);
    }
    float acc = wave_sum64(1.f / (1.f + __expf(-s0)) + 1.f / (1.f + __expf(-s1)));
    if ((threadIdx.x & 63) == 0) atomicAdd(&red, acc);
    __syncthreads();
    if (threadIdx.x == 0) atomicAdd(&ws[O_SCA + b], red);
}

__global__ __launch_bounds__(256) void k_pass4(
    const float* __restrict__ wsk1, const float* __restrict__ wsk2,
    float* __restrict__ ws) {
    const int b = threadIdx.x >> 6;
    const int lane = threadIdx.x & 63;
    __shared__ float u_s[NB][NC];
    __shared__ float a1_s[NB][NCH];
    float sca = ws[O_SCA + b];
    float sa = ws[O_SA + b * NC + lane];
    float invn = 1.f / (float)NPIX;
    u_s[b][lane] = fmaf(sa, sca * invn, invn);
    __syncthreads();
    if (lane < NCH) {
        float s = 0.f;
#pragma unroll
        for (int c = 0; c < NC; ++c) s = fmaf(wsk1[lane * NC + c], u_s[b][c], s);
        a1_s[b][lane] = fmaxf(s, 0.f);
    }
    __syncthreads();
    float s2 = 0.f;
#pragma unroll
    for (int ch = 0; ch < NCH; ++ch) s2 = fmaf(wsk2[lane * NCH + ch], a1_s[b][ch], s2);
    s2 = fmaxf(s2, 0.f);
    float mx = s2;
#pragma unroll
    for (int m = 32; m; m >>= 1) mx = fmaxf(mx, __shfl_xor(mx, m, 64));
    float e = __expf(s2 - mx);
    float sm = e;
#pragma unroll
    for (int m = 32; m; m >>= 1) sm += __shfl_xor(sm, m, 64);
    float a = e / sm;
    ws[O_K + b * NC + lane] = fmaf(a, sa * sca, 1.f - a);
}

__global__ __launch_bounds__(256) void k_pass5(
    const float* __restrict__ x, const float* __restrict__ ws,
    float* __restrict__ out) {
    const int b = blockIdx.y;
    const float* xb = x + (size_t)b * NC * NPIX;
    float* ob = out + (size_t)b * NC * NPIX;
    __shared__ float wlds[NC * NC];
    for (int i = threadIdx.x; i < NC * NC; i += 256) wlds[i] = ws[O_WT5 + i];
    __syncthreads();
    const int n2 = blockIdx.x * 256 + threadIdx.x;
    float acc[NC][2];
#pragma unroll
    for (int o = 0; o < NC; ++o) acc[o][0] = acc[o][1] = 0.f;
    for (int c = 0; c < NC; ++c) {
        const float2 xv = *(const float2*)(xb + (size_t)c * NPIX + 2 * n2);
        const float* wr = wlds + c * NC;
#pragma unroll
        for (int o = 0; o < NC; ++o) {
            acc[o][0] = fmaf(wr[o], xv.x, acc[o][0]);
            acc[o][1] = fmaf(wr[o], xv.y, acc[o][1]);
        }
    }
#pragma unroll
    for (int o = 0; o < NC; ++o) {
        const float k = ws[O_K + b * NC + o];
        float2 r;
        r.x = k + fmaxf(acc[o][0], 0.f);
        r.y = k + fmaxf(acc[o][1], 0.f);
        *(float2*)(ob + (size_t)o * NPIX + 2 * n2) = r;
    }
}

extern "C" void kernel_launch(void* const* d_in, const int* in_sizes, int n_in,
                              void* d_out, int out_size, void* d_ws, size_t ws_size,
                              hipStream_t stream) {
    const float* x    = (const float*)d_in[0];
    const float* wqr  = (const float*)d_in[1];
    const float* wvr  = (const float*)d_in[2];
    const float* wup  = (const float*)d_in[3];
    const float* wql  = (const float*)d_in[4];
    const float* wvl  = (const float*)d_in[5];
    const float* wsk1 = (const float*)d_in[6];
    const float* wsk2 = (const float*)d_in[7];
    const float* wres = (const float*)d_in[8];
    float* out = (float*)d_out;
    float* ws  = (float*)d_ws;

    dim3 blk(256);

    if (ws_size >= (size_t)WS_NEED) {
        unsigned short* xt = (unsigned short*)((char*)d_ws + XT_OFF);
        k_prepf<<<dim3(1), blk, 0, stream>>>(wqr, wvr, wql, wvl, wres, ws);
        k_Tp1<<<dim3(NTBLK, NB), blk, 0, stream>>>(x, xt, ws, ws);
        k_red<<<dim3(65, NB), blk, 0, stream>>>(ws);
        k_pass2<<<dim3(1), blk, 0, stream>>>(wup, ws);
        k_p3v<<<dim3(NPIX / (16 * 4 * TPW), NB), blk, 0, stream>>>(xt, ws);
        k_p5<<<dim3(NPIX / (16 * 4 * TPW), NB), blk, 0, stream>>>(xt, ws, wsk1, wsk2, out);
    } else {
        hipMemsetAsync(d_ws, 0, 272 * sizeof(float), stream);
        k_prep<<<dim3(1), blk, 0, stream>>>(wqr, wvr, wql, wvl, wres, ws);
        dim3 g(NPIX / (2 * 256), NB);
        k_pass1<<<g, blk, 0, stream>>>(x, ws);
        k_pass2<<<dim3(1), blk, 0, stream>>>(wup, ws);
        k_pass3<<<g, blk, 0, stream>>>(x, ws);
        k_pass4<<<dim3(1), blk, 0, stream>>>(wsk1, wsk2, ws);
        k_pass5<<<g, blk, 0, stream>>>(x, ws, out);
    }
}

// Round 10
// 135.621 us; speedup vs baseline: 1.1071x; 1.1071x over previous
//
#include <hip/hip_runtime.h>

#define NB 4
#define NC 64
#define NCH 32
#define NPIX 131072   // 32*64*64

// ---- workspace float offsets (small region, both paths) ----
#define O_SUME 0
#define O_CTX  8
#define O_QL   136
#define O_SCA  264
#define O_SA   272
#define O_AVGX 528
#define O_K    656
// fallback-path transposed weights
#define O_WT1  1024
#define WT1_S  68
#define O_WT3  6144
#define O_WT5  8192
// ---- fast-path byte offsets ----
#define AF1_OFF 4096u        // [5][2][64][8] u16 = 10240 B  (vr0,vr1,ql0,ql1,qr)
#define AF3_OFF 14336u       // [2][2][64][8] u16 = 4096 B   (vl0,vl1)
#define AF5_OFF 18432u       // [4][2][64][8] u16 = 8192 B   (wres)
#define PB_OFF  32768u       // partials [NB][65][NPBLK] f32 = 266240 B
#define PB_F    8192         // float index of PB_OFF
#define NPBLK   256          // k_Tp1 grid.x
#define TPT     8            // tiles per k_Tp1 block
#define XT_OFF  327680u      // x_t bf16: 4*131072*64*2 = 67108864 B
#define WS_NEED 67436544u

typedef short bf16x8 __attribute__((ext_vector_type(8)));
typedef float f32x4  __attribute__((ext_vector_type(4)));
typedef unsigned short u16x8 __attribute__((ext_vector_type(8)));

__device__ __forceinline__ float wave_sum64(float v) {
#pragma unroll
    for (int m = 32; m; m >>= 1) v += __shfl_xor(v, m, 64);
    return v;
}
__device__ __forceinline__ float gsum16(float v) {   // reduce over col bits (0..3)
#pragma unroll
    for (int m = 8; m; m >>= 1) v += __shfl_xor(v, m, 64);
    return v;
}
__device__ __forceinline__ unsigned short f2bf(float f) {
    unsigned u = __float_as_uint(f);
    u += 0x7FFFu + ((u >> 16) & 1u);
    return (unsigned short)(u >> 16);
}

// ================= FAST PATH =================

// prep: pack bf16 A-fragments for 16x16x32 MFMA (1 block, runs first).
__global__ __launch_bounds__(256) void k_prepf(
    const float* __restrict__ wqr, const float* __restrict__ wvr,
    const float* __restrict__ wql, const float* __restrict__ wvl,
    const float* __restrict__ wres, float* __restrict__ ws) {
    unsigned short* af1 = (unsigned short*)((char*)ws + AF1_OFF);
    unsigned short* af3 = (unsigned short*)((char*)ws + AF3_OFF);
    unsigned short* af5 = (unsigned short*)((char*)ws + AF5_OFF);
    for (int idx = threadIdx.x; idx < 5 * 2 * 64 * 8; idx += 256) {
        int j = idx & 7, lane = (idx >> 3) & 63, s = (idx >> 9) & 1, t = idx >> 10;
        int row = lane & 15, kg = lane >> 4, c = s * 32 + kg * 8 + j;
        float v;
        if (t < 2)      v = wvr[(t * 16 + row) * NC + c];
        else if (t < 4) v = wql[((t - 2) * 16 + row) * NC + c];
        else            v = (row == 0) ? wqr[c] : 0.f;
        af1[idx] = f2bf(v);
    }
    for (int idx = threadIdx.x; idx < 2 * 2 * 64 * 8; idx += 256) {
        int j = idx & 7, lane = (idx >> 3) & 63, s = (idx >> 9) & 1, t = idx >> 10;
        int row = lane & 15, kg = lane >> 4, c = s * 32 + kg * 8 + j;
        af3[idx] = f2bf(wvl[(t * 16 + row) * NC + c]);
    }
    for (int idx = threadIdx.x; idx < 4 * 2 * 64 * 8; idx += 256) {
        int j = idx & 7, lane = (idx >> 3) & 63, s = (idx >> 9) & 1, t = idx >> 10;
        int row = lane & 15, kg = lane >> 4, c = s * 32 + kg * 8 + j;
        af5[idx] = f2bf(wres[(t * 16 + row) * NC + c]);
    }
}

// Tp1: per block, loop over TPT tiles: transpose x tile -> xt (bf16) AND
// p1 MFMA accumulation (B-fragments via in-register shuffle of the
// just-transposed data). ONE reduction epilogue per block.
__global__ __launch_bounds__(256) void k_Tp1(
    const float* __restrict__ x, unsigned short* __restrict__ xt,
    const float* __restrict__ wsro, float* __restrict__ ws) {
    const int b = blockIdx.y;
    const int t = threadIdx.x;
    __shared__ float lds[64 * 65];
    __shared__ float red[65];     // 0..31 ctx, 32..63 ql, 64 sume
    for (int i = t; i < 65; i += 256) red[i] = 0.f;

    const int c = t >> 2, q = t & 3;         // load role
    const int nl = t >> 2, cq = t & 3;       // transpose-read role
    const int lane = t & 63;
    const int col = lane & 15, kg = lane >> 4;
    const int s0 = (col << 2) + (kg >> 1);
    const int s1 = s0 + 2;

    // A-fragments from packed af1 (L2-hot), loaded once
    const unsigned short* af1 = (const unsigned short*)((const char*)wsro + AF1_OFF);
    bf16x8 A[5][2];
#pragma unroll
    for (int tt = 0; tt < 5; ++tt)
#pragma unroll
        for (int s = 0; s < 2; ++s)
            A[tt][s] = *(const bf16x8*)(af1 + ((tt * 2 + s) * 64 + lane) * 8);

    float ctx[8], qla[8];
#pragma unroll
    for (int i = 0; i < 8; ++i) { ctx[i] = 0.f; qla[i] = 0.f; }
    float acc_e = 0.f;

    for (int it = 0; it < TPT; ++it) {
        const int n0 = (blockIdx.x * TPT + it) * 64;

        // ---- load + LDS transpose (proven k_T pattern) ----
        const float* src = x + (size_t)(b * NC + c) * NPIX + n0;
#pragma unroll
        for (int k = 0; k < 4; ++k) {
            float4 v = *(const float4*)(src + q * 4 + k * 16);
            lds[c * 65 + q * 4 + k * 16 + 0] = v.x;
            lds[c * 65 + q * 4 + k * 16 + 1] = v.y;
            lds[c * 65 + q * 4 + k * 16 + 2] = v.z;
            lds[c * 65 + q * 4 + k * 16 + 3] = v.w;
        }
        __syncthreads();

        // ---- xt write; o0/o1 stay live in registers ----
        u16x8 o0, o1;
#pragma unroll
        for (int i = 0; i < 8; ++i) o0[i] = f2bf(lds[(cq * 16 + i) * 65 + nl]);
#pragma unroll
        for (int i = 0; i < 8; ++i) o1[i] = f2bf(lds[(cq * 16 + 8 + i) * 65 + nl]);
        {
            unsigned short* dst = xt + ((size_t)b * NPIX + n0 + nl) * NC + cq * 16;
            *(u16x8*)(dst) = o0;
            *(u16x8*)(dst + 8) = o1;
        }
        __syncthreads();   // lds free for next tile

        // ---- B-fragments via in-register wave shuffle (verified R9) ----
        int b0w[4], b1w[4];
        const int* p0 = (const int*)&o0;
        const int* p1 = (const int*)&o1;
#pragma unroll
        for (int i = 0; i < 4; ++i) {
            int v0 = __shfl(p0[i], s0, 64);
            int v1 = __shfl(p1[i], s0, 64);
            b0w[i] = (kg & 1) ? v1 : v0;
            int w0 = __shfl(p0[i], s1, 64);
            int w1 = __shfl(p1[i], s1, 64);
            b1w[i] = (kg & 1) ? w1 : w0;
        }
        bf16x8 B0 = *(bf16x8*)b0w;
        bf16x8 B1 = *(bf16x8*)b1w;

        // ---- p1 math (verified) ----
        f32x4 c6 = {0.f, 0.f, 0.f, 0.f};
        c6 = __builtin_amdgcn_mfma_f32_16x16x32_bf16(A[4][0], B0, c6, 0, 0, 0);
        c6 = __builtin_amdgcn_mfma_f32_16x16x32_bf16(A[4][1], B1, c6, 0, 0, 0);
        float e = __expf(fmaxf(c6[0], 0.f));
        e = __shfl(e, col, 64);          // row-0 value for pixel col
        acc_e += e;                       // counted 4x (kg copies), fixed below

        f32x4 c0 = {0.f, 0.f, 0.f, 0.f}, c1 = {0.f, 0.f, 0.f, 0.f};
        c0 = __builtin_amdgcn_mfma_f32_16x16x32_bf16(A[0][0], B0, c0, 0, 0, 0);
        c0 = __builtin_amdgcn_mfma_f32_16x16x32_bf16(A[0][1], B1, c0, 0, 0, 0);
        c1 = __builtin_amdgcn_mfma_f32_16x16x32_bf16(A[1][0], B0, c1, 0, 0, 0);
        c1 = __builtin_amdgcn_mfma_f32_16x16x32_bf16(A[1][1], B1, c1, 0, 0, 0);
#pragma unroll
        for (int r = 0; r < 4; ++r) {
            ctx[r]     += fmaxf(c0[r], 0.f) * e;
            ctx[4 + r] += fmaxf(c1[r], 0.f) * e;
        }
        c0 = f32x4{0.f, 0.f, 0.f, 0.f}; c1 = f32x4{0.f, 0.f, 0.f, 0.f};
        c0 = __builtin_amdgcn_mfma_f32_16x16x32_bf16(A[2][0], B0, c0, 0, 0, 0);
        c0 = __builtin_amdgcn_mfma_f32_16x16x32_bf16(A[2][1], B1, c0, 0, 0, 0);
        c1 = __builtin_amdgcn_mfma_f32_16x16x32_bf16(A[3][0], B0, c1, 0, 0, 0);
        c1 = __builtin_amdgcn_mfma_f32_16x16x32_bf16(A[3][1], B1, c1, 0, 0, 0);
#pragma unroll
        for (int r = 0; r < 4; ++r) {
            qla[r]     += fmaxf(c0[r], 0.f);
            qla[4 + r] += fmaxf(c1[r], 0.f);
        }
    }

    // ---- reduction epilogue, once per block (proven k_p1 pattern) ----
    acc_e = wave_sum64(acc_e) * 0.25f;
    if (lane == 0) atomicAdd(&red[64], acc_e);
#pragma unroll
    for (int i = 0; i < 8; ++i) {
        float v = gsum16(ctx[i]);
        float qv = gsum16(qla[i]);
        if (col == 0) {
            int ch = (i >> 2) * 16 + kg * 4 + (i & 3);
            atomicAdd(&red[ch], v);       // LDS atomics, block-scope
            atomicAdd(&red[32 + ch], qv);
        }
    }
    __syncthreads();
    float* pb = ws + PB_F;
    if (t < 65)
        pb[((size_t)b * 65 + t) * NPBLK + blockIdx.x] = red[t];
}

// red: parallel partial reduction -> SUME/CTX/QL; zero SCA. grid (65, NB).
__global__ __launch_bounds__(256) void k_red(float* __restrict__ ws) {
    const int slot = blockIdx.x;   // 0..64
    const int b = blockIdx.y;
    const float* p = ws + PB_F + ((size_t)b * 65 + slot) * NPBLK;
    float s = (threadIdx.x < NPBLK) ? p[threadIdx.x] : 0.f;
    s = wave_sum64(s);
    __shared__ float r4[4];
    if ((threadIdx.x & 63) == 0) r4[threadIdx.x >> 6] = s;
    __syncthreads();
    if (threadIdx.x == 0) {
        float tot = r4[0] + r4[1] + r4[2] + r4[3];
        if (slot < 32)      ws[O_CTX + b * NCH + slot] = tot;
        else if (slot < 64) ws[O_QL + b * NCH + (slot - 32)] = tot;
        else { ws[O_SUME + b] = tot; ws[O_SCA + b] = 0.f; }
    }
}

#define TPW 8
// p3 (MFMA): S_ca = sum_n sigmoid(sum_ch avgx[ch]*relu(wvl x)); 1 atomic/block
__global__ __launch_bounds__(256) void k_p3v(
    const unsigned short* __restrict__ xt, float* __restrict__ ws) {
    const int b = blockIdx.y;
    const int lane = threadIdx.x & 63;
    const int wid = blockIdx.x * 4 + (threadIdx.x >> 6);
    const int col = lane & 15, kg = lane >> 4;
    const unsigned short* af3 = (const unsigned short*)((const char*)ws + AF3_OFF);

    __shared__ float red;
    if (threadIdx.x == 0) red = 0.f;
    __syncthreads();

    bf16x8 A[2][2];
#pragma unroll
    for (int t = 0; t < 2; ++t)
#pragma unroll
        for (int s = 0; s < 2; ++s)
            A[t][s] = *(const bf16x8*)(af3 + ((t * 2 + s) * 64 + lane) * 8);
    float ax0[4], ax1[4];
#pragma unroll
    for (int r = 0; r < 4; ++r) {
        ax0[r] = ws[O_AVGX + b * NCH + kg * 4 + r];
        ax1[r] = ws[O_AVGX + b * NCH + 16 + kg * 4 + r];
    }

    float acc = 0.f;
    for (int it = 0; it < TPW; ++it) {
        const int n0 = (wid * TPW + it) * 16;
        const unsigned short* xr = xt + ((size_t)b * NPIX + n0 + col) * NC + kg * 8;
        bf16x8 B0 = *(const bf16x8*)(xr);
        bf16x8 B1 = *(const bf16x8*)(xr + 32);
        f32x4 c0 = {0.f, 0.f, 0.f, 0.f}, c1 = {0.f, 0.f, 0.f, 0.f};
        c0 = __builtin_amdgcn_mfma_f32_16x16x32_bf16(A[0][0], B0, c0, 0, 0, 0);
        c0 = __builtin_amdgcn_mfma_f32_16x16x32_bf16(A[0][1], B1, c0, 0, 0, 0);
        c1 = __builtin_amdgcn_mfma_f32_16x16x32_bf16(A[1][0], B0, c1, 0, 0, 0);
        c1 = __builtin_amdgcn_mfma_f32_16x16x32_bf16(A[1][1], B1, c1, 0, 0, 0);
        float sp = 0.f;
#pragma unroll
        for (int r = 0; r < 4; ++r) {
            sp = fmaf(ax0[r], fmaxf(c0[r], 0.f), sp);
            sp = fmaf(ax1[r], fmaxf(c1[r], 0.f), sp);
        }
        sp += __shfl_xor(sp, 16, 64);     // reduce over kg
        sp += __shfl_xor(sp, 32, 64);
        acc += 1.f / (1.f + __expf(-sp)); // every pixel counted 4x (kg copies)
    }
    acc = wave_sum64(acc) * 0.25f;
    if (lane == 0) atomicAdd(&red, acc);
    __syncthreads();
    if (threadIdx.x == 0) atomicAdd(&ws[O_SCA + b], red);
}

// p5: SK gating (fused) then out = K[b,o] + relu(wres x) via SWAPPED MFMA:
// D[px][o] -> each lane's 4 regs are 4 consecutive n -> float4 stores.
__global__ __launch_bounds__(256) void k_p5(
    const unsigned short* __restrict__ xt, const float* __restrict__ ws,
    const float* __restrict__ wsk1, const float* __restrict__ wsk2,
    float* __restrict__ out) {
    const int b = blockIdx.y;
    const int tid = threadIdx.x;
    const int lane = tid & 63;
    const int wid = blockIdx.x * 4 + (tid >> 6);
    const int col = lane & 15, kg = lane >> 4;
    const unsigned short* af5 = (const unsigned short*)((const char*)ws + AF5_OFF);

    __shared__ float u_s[NC];
    __shared__ float a1_s[NCH];
    __shared__ float K_s[NC];

    // ---- fused pass4 (redundant per block) ----
    const float invn = 1.f / (float)NPIX;
    if (tid < NC) {
        float sca = ws[O_SCA + b];
        float sa = ws[O_SA + b * NC + tid];
        u_s[tid] = fmaf(sa, sca * invn, invn);
    }
    __syncthreads();
    if (tid < NCH) {
        float s = 0.f;
#pragma unroll
        for (int c = 0; c < NC; ++c) s = fmaf(wsk1[tid * NC + c], u_s[c], s);
        a1_s[tid] = fmaxf(s, 0.f);
    }
    __syncthreads();
    if (tid < NC) {
        float s2 = 0.f;
#pragma unroll
        for (int ch = 0; ch < NCH; ++ch) s2 = fmaf(wsk2[tid * NCH + ch], a1_s[ch], s2);
        s2 = fmaxf(s2, 0.f);
        float mx = s2;
#pragma unroll
        for (int m = 32; m; m >>= 1) mx = fmaxf(mx, __shfl_xor(mx, m, 64));
        float e = __expf(s2 - mx);
        float sm = e;
#pragma unroll
        for (int m = 32; m; m >>= 1) sm += __shfl_xor(sm, m, 64);
        float a = e / sm;
        float sca = ws[O_SCA + b];
        float sa = ws[O_SA + b * NC + tid];
        K_s[tid] = fmaf(a, sa * sca, 1.f - a);
    }
    __syncthreads();

    bf16x8 A[4][2];
#pragma unroll
    for (int t = 0; t < 4; ++t)
#pragma unroll
        for (int s = 0; s < 2; ++s)
            A[t][s] = *(const bf16x8*)(af5 + ((t * 2 + s) * 64 + lane) * 8);
    float kvc[4];
#pragma unroll
    for (int t = 0; t < 4; ++t) kvc[t] = K_s[t * 16 + col];

    for (int it = 0; it < TPW; ++it) {
        const int n0 = (wid * TPW + it) * 16;
        const unsigned short* xr = xt + ((size_t)b * NPIX + n0 + col) * NC + kg * 8;
        bf16x8 B0 = *(const bf16x8*)(xr);
        bf16x8 B1 = *(const bf16x8*)(xr + 32);
#pragma unroll
        for (int t = 0; t < 4; ++t) {
            f32x4 cc = {0.f, 0.f, 0.f, 0.f};
            cc = __builtin_amdgcn_mfma_f32_16x16x32_bf16(B0, A[t][0], cc, 0, 0, 0);
            cc = __builtin_amdgcn_mfma_f32_16x16x32_bf16(B1, A[t][1], cc, 0, 0, 0);
            float4 r;
            r.x = kvc[t] + fmaxf(cc[0], 0.f);
            r.y = kvc[t] + fmaxf(cc[1], 0.f);
            r.z = kvc[t] + fmaxf(cc[2], 0.f);
            r.w = kvc[t] + fmaxf(cc[3], 0.f);
            *(float4*)(out + ((size_t)(b * NC + t * 16 + col)) * NPIX + n0 + kg * 4) = r;
        }
    }
}

// ================= shared small kernel (p2) =================
__global__ __launch_bounds__(256) void k_pass2(
    const float* __restrict__ wup, float* __restrict__ ws) {
    const int b = threadIdx.x >> 6;
    const int lane = threadIdx.x & 63;
    __shared__ float ln_s[NB][NCH];
    float se = ws[O_SUME + b];
    float ctx = (lane < NCH) ? (ws[O_CTX + b * NCH + lane] / se) : 0.f;
    float v = ctx, v2 = ctx * ctx;
#pragma unroll
    for (int m = 16; m; m >>= 1) { v += __shfl_xor(v, m, 64); v2 += __shfl_xor(v2, m, 64); }
    float mu = v / (float)NCH;
    float var = v2 / (float)NCH - mu * mu;
    float lnv = (ctx - mu) * rsqrtf(var + 1e-5f);
    if (lane < NCH) ln_s[b][lane] = lnv;
    __syncthreads();
    float s = 0.f;
#pragma unroll
    for (int ch = 0; ch < NCH; ++ch) s = fmaf(wup[lane * NCH + ch], ln_s[b][ch], s);
    ws[O_SA + b * NC + lane] = fminf(fmaxf((s + 3.f) * (1.f / 6.f), 0.f), 1.f);
    if (lane < NCH) {
        float l = ws[O_QL + b * NCH + lane] * (1.f / (float)NPIX);
        float mx = l;
#pragma unroll
        for (int m = 16; m; m >>= 1) mx = fmaxf(mx, __shfl_xor(mx, m, 64));
        float e = __expf(l - mx);
        float sm = e;
#pragma unroll
        for (int m = 16; m; m >>= 1) sm += __shfl_xor(sm, m, 64);
        ws[O_AVGX + b * NCH + lane] = e / sm;
    }
}

// ================= FALLBACK PATH (R2, passing) =================
__global__ __launch_bounds__(256) void k_prep(
    const float* __restrict__ wqr, const float* __restrict__ wvr,
    const float* __restrict__ wql, const float* __restrict__ wvl,
    const float* __restrict__ wres, float* __restrict__ ws) {
    for (int i = threadIdx.x; i < NC * WT1_S; i += 256) {
        int c = i / WT1_S, j = i % WT1_S;
        float v = 0.f;
        if (j == 0)       v = wqr[c];
        else if (j <= 32) v = wvr[(j - 1) * NC + c];
        else if (j <= 64) v = wql[(j - 33) * NC + c];
        ws[O_WT1 + i] = v;
    }
    for (int i = threadIdx.x; i < NC * NCH; i += 256) {
        int c = i / NCH, ch = i % NCH;
        ws[O_WT3 + i] = wvl[ch * NC + c];
    }
    for (int i = threadIdx.x; i < NC * NC; i += 256) {
        int c = i / NC, o = i % NC;
        ws[O_WT5 + i] = wres[o * NC + c];
    }
}

__global__ __launch_bounds__(256) void k_pass1(
    const float* __restrict__ x, float* __restrict__ ws) {
    const int b = blockIdx.y;
    const float* xb = x + (size_t)b * NC * NPIX;
    __shared__ float wlds[NC * WT1_S];
    __shared__ float red[1 + 2 * NCH];
    for (int i = threadIdx.x; i < NC * WT1_S; i += 256) wlds[i] = ws[O_WT1 + i];
    for (int i = threadIdx.x; i < 1 + 2 * NCH; i += 256) red[i] = 0.f;
    __syncthreads();
    const int n2 = blockIdx.x * 256 + threadIdx.x;
    float dqr0 = 0.f, dqr1 = 0.f;
    float dv[NCH][2], dq[NCH][2];
#pragma unroll
    for (int i = 0; i < NCH; ++i) { dv[i][0] = dv[i][1] = 0.f; dq[i][0] = dq[i][1] = 0.f; }
    for (int c = 0; c < NC; ++c) {
        const float2 xv = *(const float2*)(xb + (size_t)c * NPIX + 2 * n2);
        const float* wr = wlds + c * WT1_S;
        dqr0 = fmaf(wr[0], xv.x, dqr0);
        dqr1 = fmaf(wr[0], xv.y, dqr1);
#pragma unroll
        for (int ch = 0; ch < NCH; ++ch) {
            const float wv = wr[1 + ch], wq = wr[33 + ch];
            dv[ch][0] = fmaf(wv, xv.x, dv[ch][0]);
            dv[ch][1] = fmaf(wv, xv.y, dv[ch][1]);
            dq[ch][0] = fmaf(wq, xv.x, dq[ch][0]);
            dq[ch][1] = fmaf(wq, xv.y, dq[ch][1]);
        }
    }
    const float e0 = __expf(fmaxf(dqr0, 0.f));
    const float e1 = __expf(fmaxf(dqr1, 0.f));
    float acc_e = wave_sum64(e0 + e1);
    if ((threadIdx.x & 63) == 0) atomicAdd(&red[0], acc_e);
#pragma unroll
    for (int ch = 0; ch < NCH; ++ch) {
        float v = wave_sum64(fmaxf(dv[ch][0], 0.f) * e0 + fmaxf(dv[ch][1], 0.f) * e1);
        float q = wave_sum64(fmaxf(dq[ch][0], 0.f) + fmaxf(dq[ch][1], 0.f));
        if ((threadIdx.x & 63) == 0) { atomicAdd(&red[1 + ch], v); atomicAdd(&red[1 + NCH + ch], q); }
    }
    __syncthreads();
    if (threadIdx.x == 0) atomicAdd(&ws[O_SUME + b], red[0]);
    if (threadIdx.x < NCH) {
        atomicAdd(&ws[O_CTX + b * NCH + threadIdx.x], red[1 + threadIdx.x]);
        atomicAdd(&ws[O_QL  + b * NCH + threadIdx.x], red[1 + NCH + threadIdx.x]);
    }
}

__global__ __launch_bounds__(256) void k_pass3(
    const float* __restrict__ x, float* __restrict__ ws) {
    const int b = blockIdx.y;
    const float* xb = x + (size_t)b * NC * NPIX;
    __shared__ float wlds[NC * NCH];
    __shared__ float red;
    for (int i = threadIdx.x; i < NC * NCH; i += 256) wlds[i] = ws[O_WT3 + i];
    if (threadIdx.x == 0) red = 0.f;
    __syncthreads();
    const int n2 = blockIdx.x * 256 + threadIdx.x;
    float dv[NCH][2];
#pragma unroll
    for (int i = 0; i < NCH; ++i) dv[i][0] = dv[i][1] = 0.f;
    for (int c = 0; c < NC; ++c) {
        const float2 xv = *(const float2*)(xb + (size_t)c * NPIX + 2 * n2);
        const float* wr = wlds + c * NCH;
#pragma unroll
        for (int ch = 0; ch < NCH; ++ch) {
            dv[ch][0] = fmaf(wr[ch], xv.x, dv[ch][0]);
            dv[ch][1] = fmaf(wr[ch], xv.y, dv[ch][1]);
        }
    }
    float s0 = 0.f, s1 = 0.f;
#pragma unroll
    for (int ch = 0; ch < NCH; ++ch) {
        const float ax = ws[O_AVGX + b * NCH + ch];
        s0 = fmaf(ax, fmaxf(dv[ch][0], 0.f), s0);
        s1 = fmaf(ax, fmaxf(dv[ch][1], 0.f), s1);
    }
    float acc = wave_sum64(1.f / (1.f + __expf(-s0)) + 1.f / (1.f + __expf(-s1)));
    if ((threadIdx.x & 63) == 0) atomicAdd(&red, acc);
    __syncthreads();
    if (threadIdx.x == 0) atomicAdd(&ws[O_SCA + b], red);
}

__global__ __launch_bounds__(256) void k_pass4(
    const float* __restrict__ wsk1, const float* __restrict__ wsk2,
    float* __restrict__ ws) {
    const int b = threadIdx.x >> 6;
    const int lane = threadIdx.x & 63;
    __shared__ float u_s[NB][NC];
    __shared__ float a1_s[NB][NCH];
    float sca = ws[O_SCA + b];
    float sa = ws[O_SA + b * NC + lane];
    float invn = 1.f / (float)NPIX;
    u_s[b][lane] = fmaf(sa, sca * invn, invn);
    __syncthreads();
    if (lane < NCH) {
        float s = 0.f;
#pragma unroll
        for (int c = 0; c < NC; ++c) s = fmaf(wsk1[lane * NC + c], u_s[b][c], s);
        a1_s[b][lane] = fmaxf(s, 0.f);
    }
    __syncthreads();
    float s2 = 0.f;
#pragma unroll
    for (int ch = 0; ch < NCH; ++ch) s2 = fmaf(wsk2[lane * NCH + ch], a1_s[b][ch], s2);
    s2 = fmaxf(s2, 0.f);
    float mx = s2;
#pragma unroll
    for (int m = 32; m; m >>= 1) mx = fmaxf(mx, __shfl_xor(mx, m, 64));
    float e = __expf(s2 - mx);
    float sm = e;
#pragma unroll
    for (int m = 32; m; m >>= 1) sm += __shfl_xor(sm, m, 64);
    float a = e / sm;
    ws[O_K + b * NC + lane] = fmaf(a, sa * sca, 1.f - a);
}

__global__ __launch_bounds__(256) void k_pass5(
    const float* __restrict__ x, const float* __restrict__ ws,
    float* __restrict__ out) {
    const int b = blockIdx.y;
    const float* xb = x + (size_t)b * NC * NPIX;
    float* ob = out + (size_t)b * NC * NPIX;
    __shared__ float wlds[NC * NC];
    for (int i = threadIdx.x; i < NC * NC; i += 256) wlds[i] = ws[O_WT5 + i];
    __syncthreads();
    const int n2 = blockIdx.x * 256 + threadIdx.x;
    float acc[NC][2];
#pragma unroll
    for (int o = 0; o < NC; ++o) acc[o][0] = acc[o][1] = 0.f;
    for (int c = 0; c < NC; ++c) {
        const float2 xv = *(const float2*)(xb + (size_t)c * NPIX + 2 * n2);
        const float* wr = wlds + c * NC;
#pragma unroll
        for (int o = 0; o < NC; ++o) {
            acc[o][0] = fmaf(wr[o], xv.x, acc[o][0]);
            acc[o][1] = fmaf(wr[o], xv.y, acc[o][1]);
        }
    }
#pragma unroll
    for (int o = 0; o < NC; ++o) {
        const float k = ws[O_K + b * NC + o];
        float2 r;
        r.x = k + fmaxf(acc[o][0], 0.f);
        r.y = k + fmaxf(acc[o][1], 0.f);
        *(float2*)(ob + (size_t)o * NPIX + 2 * n2) = r;
    }
}

extern "C" void kernel_launch(void* const* d_in, const int* in_sizes, int n_in,
                              void* d_out, int out_size, void* d_ws, size_t ws_size,
                              hipStream_t stream) {
    const float* x    = (const float*)d_in[0];
    const float* wqr  = (const float*)d_in[1];
    const float* wvr  = (const float*)d_in[2];
    const float* wup  = (const float*)d_in[3];
    const float* wql  = (const float*)d_in[4];
    const float* wvl  = (const float*)d_in[5];
    const float* wsk1 = (const float*)d_in[6];
    const float* wsk2 = (const float*)d_in[7];
    const float* wres = (const float*)d_in[8];
    float* out = (float*)d_out;
    float* ws  = (float*)d_ws;

    dim3 blk(256);

    if (ws_size >= (size_t)WS_NEED) {
        unsigned short* xt = (unsigned short*)((char*)d_ws + XT_OFF);
        k_prepf<<<dim3(1), blk, 0, stream>>>(wqr, wvr, wql, wvl, wres, ws);
        k_Tp1<<<dim3(NPBLK, NB), blk, 0, stream>>>(x, xt, ws, ws);
        k_red<<<dim3(65, NB), blk, 0, stream>>>(ws);
        k_pass2<<<dim3(1), blk, 0, stream>>>(wup, ws);
        k_p3v<<<dim3(NPIX / (16 * 4 * TPW), NB), blk, 0, stream>>>(xt, ws);
        k_p5<<<dim3(NPIX / (16 * 4 * TPW), NB), blk, 0, stream>>>(xt, ws, wsk1, wsk2, out);
    } else {
        hipMemsetAsync(d_ws, 0, 272 * sizeof(float), stream);
        k_prep<<<dim3(1), blk, 0, stream>>>(wqr, wvr, wql, wvl, wres, ws);
        dim3 g(NPIX / (2 * 256), NB);
        k_pass1<<<g, blk, 0, stream>>>(x, ws);
        k_pass2<<<dim3(1), blk, 0, stream>>>(wup, ws);
        k_pass3<<<g, blk, 0, stream>>>(x, ws);
        k_pass4<<<dim3(1), blk, 0, stream>>>(wsk1, wsk2, ws);
        k_pass5<<<g, blk, 0, stream>>>(x, ws, out);
    }
}

// Round 11
// 134.944 us; speedup vs baseline: 1.1127x; 1.0050x over previous
//
#include <hip/hip_runtime.h>

#define NB 4
#define NC 64
#define NCH 32
#define NPIX 131072   // 32*64*64

// ---- workspace float offsets (small region, both paths) ----
#define O_SUME 0
#define O_CTX  8
#define O_QL   136
#define O_SCA  264
#define O_SA   272
#define O_AVGX 528
#define O_K    656
// fallback-path transposed weights
#define O_WT1  1024
#define WT1_S  68
#define O_WT3  6144
#define O_WT5  8192
// ---- fast-path byte offsets ----
#define AF1_OFF 4096u        // [5][2][64][8] u16 = 10240 B  (vr0,vr1,ql0,ql1,qr)
#define AF3_OFF 14336u       // [2][2][64][8] u16 = 4096 B   (vl0,vl1)
#define AF5_OFF 18432u       // [4][2][64][8] u16 = 8192 B   (wres)
#define PB_OFF  32768u       // partials [NB][65][NPBLK] f32 = 266240 B
#define PB_F    8192         // float index of PB_OFF
#define NPBLK   256          // k_Tp1 grid.x
#define TPT     8            // tiles per k_Tp1 block
#define XT_OFF  327680u      // x_t bf16: 4*131072*64*2 = 67108864 B
#define WS_NEED 67436544u

typedef short bf16x8 __attribute__((ext_vector_type(8)));
typedef float f32x4  __attribute__((ext_vector_type(4)));
typedef unsigned short u16x8 __attribute__((ext_vector_type(8)));

__device__ __forceinline__ float wave_sum64(float v) {
#pragma unroll
    for (int m = 32; m; m >>= 1) v += __shfl_xor(v, m, 64);
    return v;
}
__device__ __forceinline__ float gsum16(float v) {   // reduce over col bits (0..3)
#pragma unroll
    for (int m = 8; m; m >>= 1) v += __shfl_xor(v, m, 64);
    return v;
}
__device__ __forceinline__ unsigned short f2bf(float f) {
    unsigned u = __float_as_uint(f);
    u += 0x7FFFu + ((u >> 16) & 1u);
    return (unsigned short)(u >> 16);
}

// ================= FAST PATH =================

// prep: pack bf16 A-fragments for 16x16x32 MFMA (1 block, runs first).
__global__ __launch_bounds__(256) void k_prepf(
    const float* __restrict__ wqr, const float* __restrict__ wvr,
    const float* __restrict__ wql, const float* __restrict__ wvl,
    const float* __restrict__ wres, float* __restrict__ ws) {
    unsigned short* af1 = (unsigned short*)((char*)ws + AF1_OFF);
    unsigned short* af3 = (unsigned short*)((char*)ws + AF3_OFF);
    unsigned short* af5 = (unsigned short*)((char*)ws + AF5_OFF);
    for (int idx = threadIdx.x; idx < 5 * 2 * 64 * 8; idx += 256) {
        int j = idx & 7, lane = (idx >> 3) & 63, s = (idx >> 9) & 1, t = idx >> 10;
        int row = lane & 15, kg = lane >> 4, c = s * 32 + kg * 8 + j;
        float v;
        if (t < 2)      v = wvr[(t * 16 + row) * NC + c];
        else if (t < 4) v = wql[((t - 2) * 16 + row) * NC + c];
        else            v = (row == 0) ? wqr[c] : 0.f;
        af1[idx] = f2bf(v);
    }
    for (int idx = threadIdx.x; idx < 2 * 2 * 64 * 8; idx += 256) {
        int j = idx & 7, lane = (idx >> 3) & 63, s = (idx >> 9) & 1, t = idx >> 10;
        int row = lane & 15, kg = lane >> 4, c = s * 32 + kg * 8 + j;
        af3[idx] = f2bf(wvl[(t * 16 + row) * NC + c]);
    }
    for (int idx = threadIdx.x; idx < 4 * 2 * 64 * 8; idx += 256) {
        int j = idx & 7, lane = (idx >> 3) & 63, s = (idx >> 9) & 1, t = idx >> 10;
        int row = lane & 15, kg = lane >> 4, c = s * 32 + kg * 8 + j;
        af5[idx] = f2bf(wres[(t * 16 + row) * NC + c]);
    }
}

// Tp1: per block, TPT tiles, DOUBLE-BUFFERED: prefetch tile i+1's global
// loads under tile i's compute. One __syncthreads per tile.
__global__ __launch_bounds__(256) void k_Tp1(
    const float* __restrict__ x, unsigned short* __restrict__ xt,
    const float* __restrict__ wsro, float* __restrict__ ws) {
    const int b = blockIdx.y;
    const int t = threadIdx.x;
    __shared__ float lds[2][64 * 65];
    __shared__ float red[65];     // 0..31 ctx, 32..63 ql, 64 sume
    for (int i = t; i < 65; i += 256) red[i] = 0.f;

    const int c = t >> 2, q = t & 3;         // load role
    const int nl = t >> 2, cq = t & 3;       // transpose-read role
    const int lane = t & 63;
    const int col = lane & 15, kg = lane >> 4;
    const int s0 = (col << 2) + (kg >> 1);
    const int s1 = s0 + 2;

    // A-fragments from packed af1 (L2-hot), loaded once
    const unsigned short* af1 = (const unsigned short*)((const char*)wsro + AF1_OFF);
    bf16x8 A[5][2];
#pragma unroll
    for (int tt = 0; tt < 5; ++tt)
#pragma unroll
        for (int s = 0; s < 2; ++s)
            A[tt][s] = *(const bf16x8*)(af1 + ((tt * 2 + s) * 64 + lane) * 8);

    float ctx[8], qla[8];
#pragma unroll
    for (int i = 0; i < 8; ++i) { ctx[i] = 0.f; qla[i] = 0.f; }
    float acc_e = 0.f;

    // prefetch tile 0
    const float* srcbase = x + (size_t)(b * NC + c) * NPIX + q * 4;
    float4 pf0, pf1, pf2, pf3;
    {
        const float* src = srcbase + (size_t)(blockIdx.x * TPT) * 64;
        pf0 = *(const float4*)(src);
        pf1 = *(const float4*)(src + 16);
        pf2 = *(const float4*)(src + 32);
        pf3 = *(const float4*)(src + 48);
    }

    for (int it = 0; it < TPT; ++it) {
        const int n0 = (blockIdx.x * TPT + it) * 64;
        float* buf = lds[it & 1];

        // ---- LDS write of the prefetched tile ----
        float* br = buf + c * 65 + q * 4;
        br[0]  = pf0.x; br[1]  = pf0.y; br[2]  = pf0.z; br[3]  = pf0.w;
        br[16] = pf1.x; br[17] = pf1.y; br[18] = pf1.z; br[19] = pf1.w;
        br[32] = pf2.x; br[33] = pf2.y; br[34] = pf2.z; br[35] = pf2.w;
        br[48] = pf3.x; br[49] = pf3.y; br[50] = pf3.z; br[51] = pf3.w;
        __syncthreads();

        // ---- issue next tile's global loads (latency hidden by compute) ----
        if (it + 1 < TPT) {
            const float* src = srcbase + (size_t)(blockIdx.x * TPT + it + 1) * 64;
            pf0 = *(const float4*)(src);
            pf1 = *(const float4*)(src + 16);
            pf2 = *(const float4*)(src + 32);
            pf3 = *(const float4*)(src + 48);
        }

        // ---- transpose-read + cvt; xt write; o0/o1 stay live ----
        u16x8 o0, o1;
#pragma unroll
        for (int i = 0; i < 8; ++i) o0[i] = f2bf(buf[(cq * 16 + i) * 65 + nl]);
#pragma unroll
        for (int i = 0; i < 8; ++i) o1[i] = f2bf(buf[(cq * 16 + 8 + i) * 65 + nl]);
        {
            unsigned short* dst = xt + ((size_t)b * NPIX + n0 + nl) * NC + cq * 16;
            *(u16x8*)(dst) = o0;
            *(u16x8*)(dst + 8) = o1;
        }

        // ---- B-fragments via in-register wave shuffle (verified) ----
        int b0w[4], b1w[4];
        const int* p0 = (const int*)&o0;
        const int* p1 = (const int*)&o1;
#pragma unroll
        for (int i = 0; i < 4; ++i) {
            int v0 = __shfl(p0[i], s0, 64);
            int v1 = __shfl(p1[i], s0, 64);
            b0w[i] = (kg & 1) ? v1 : v0;
            int w0 = __shfl(p0[i], s1, 64);
            int w1 = __shfl(p1[i], s1, 64);
            b1w[i] = (kg & 1) ? w1 : w0;
        }
        bf16x8 B0 = *(bf16x8*)b0w;
        bf16x8 B1 = *(bf16x8*)b1w;

        // ---- p1 math (verified) ----
        f32x4 c6 = {0.f, 0.f, 0.f, 0.f};
        c6 = __builtin_amdgcn_mfma_f32_16x16x32_bf16(A[4][0], B0, c6, 0, 0, 0);
        c6 = __builtin_amdgcn_mfma_f32_16x16x32_bf16(A[4][1], B1, c6, 0, 0, 0);
        float e = __expf(fmaxf(c6[0], 0.f));
        e = __shfl(e, col, 64);          // row-0 value for pixel col
        acc_e += e;                       // counted 4x (kg copies), fixed below

        f32x4 c0 = {0.f, 0.f, 0.f, 0.f}, c1 = {0.f, 0.f, 0.f, 0.f};
        c0 = __builtin_amdgcn_mfma_f32_16x16x32_bf16(A[0][0], B0, c0, 0, 0, 0);
        c0 = __builtin_amdgcn_mfma_f32_16x16x32_bf16(A[0][1], B1, c0, 0, 0, 0);
        c1 = __builtin_amdgcn_mfma_f32_16x16x32_bf16(A[1][0], B0, c1, 0, 0, 0);
        c1 = __builtin_amdgcn_mfma_f32_16x16x32_bf16(A[1][1], B1, c1, 0, 0, 0);
#pragma unroll
        for (int r = 0; r < 4; ++r) {
            ctx[r]     += fmaxf(c0[r], 0.f) * e;
            ctx[4 + r] += fmaxf(c1[r], 0.f) * e;
        }
        c0 = f32x4{0.f, 0.f, 0.f, 0.f}; c1 = f32x4{0.f, 0.f, 0.f, 0.f};
        c0 = __builtin_amdgcn_mfma_f32_16x16x32_bf16(A[2][0], B0, c0, 0, 0, 0);
        c0 = __builtin_amdgcn_mfma_f32_16x16x32_bf16(A[2][1], B1, c0, 0, 0, 0);
        c1 = __builtin_amdgcn_mfma_f32_16x16x32_bf16(A[3][0], B0, c1, 0, 0, 0);
        c1 = __builtin_amdgcn_mfma_f32_16x16x32_bf16(A[3][1], B1, c1, 0, 0, 0);
#pragma unroll
        for (int r = 0; r < 4; ++r) {
            qla[r]     += fmaxf(c0[r], 0.f);
            qla[4 + r] += fmaxf(c1[r], 0.f);
        }
    }

    // ---- reduction epilogue, once per block ----
    acc_e = wave_sum64(acc_e) * 0.25f;
    if (lane == 0) atomicAdd(&red[64], acc_e);
#pragma unroll
    for (int i = 0; i < 8; ++i) {
        float v = gsum16(ctx[i]);
        float qv = gsum16(qla[i]);
        if (col == 0) {
            int ch = (i >> 2) * 16 + kg * 4 + (i & 3);
            atomicAdd(&red[ch], v);       // LDS atomics, block-scope
            atomicAdd(&red[32 + ch], qv);
        }
    }
    __syncthreads();
    float* pb = ws + PB_F;
    if (t < 65)
        pb[((size_t)b * 65 + t) * NPBLK + blockIdx.x] = red[t];
}

// red: parallel partial reduction -> SUME/CTX/QL; zero SCA. grid (65, NB).
__global__ __launch_bounds__(256) void k_red(float* __restrict__ ws) {
    const int slot = blockIdx.x;   // 0..64
    const int b = blockIdx.y;
    const float* p = ws + PB_F + ((size_t)b * 65 + slot) * NPBLK;
    float s = (threadIdx.x < NPBLK) ? p[threadIdx.x] : 0.f;
    s = wave_sum64(s);
    __shared__ float r4[4];
    if ((threadIdx.x & 63) == 0) r4[threadIdx.x >> 6] = s;
    __syncthreads();
    if (threadIdx.x == 0) {
        float tot = r4[0] + r4[1] + r4[2] + r4[3];
        if (slot < 32)      ws[O_CTX + b * NCH + slot] = tot;
        else if (slot < 64) ws[O_QL + b * NCH + (slot - 32)] = tot;
        else { ws[O_SUME + b] = tot; ws[O_SCA + b] = 0.f; }
    }
}

#define TPW 8
// p3 (MFMA): S_ca = sum_n sigmoid(sum_ch avgx[ch]*relu(wvl x)); 1 atomic/block
__global__ __launch_bounds__(256) void k_p3v(
    const unsigned short* __restrict__ xt, float* __restrict__ ws) {
    const int b = blockIdx.y;
    const int lane = threadIdx.x & 63;
    const int wid = blockIdx.x * 4 + (threadIdx.x >> 6);
    const int col = lane & 15, kg = lane >> 4;
    const unsigned short* af3 = (const unsigned short*)((const char*)ws + AF3_OFF);

    __shared__ float red;
    if (threadIdx.x == 0) red = 0.f;
    __syncthreads();

    bf16x8 A[2][2];
#pragma unroll
    for (int t = 0; t < 2; ++t)
#pragma unroll
        for (int s = 0; s < 2; ++s)
            A[t][s] = *(const bf16x8*)(af3 + ((t * 2 + s) * 64 + lane) * 8);
    float ax0[4], ax1[4];
#pragma unroll
    for (int r = 0; r < 4; ++r) {
        ax0[r] = ws[O_AVGX + b * NCH + kg * 4 + r];
        ax1[r] = ws[O_AVGX + b * NCH + 16 + kg * 4 + r];
    }

    float acc = 0.f;
    for (int it = 0; it < TPW; ++it) {
        const int n0 = (wid * TPW + it) * 16;
        const unsigned short* xr = xt + ((size_t)b * NPIX + n0 + col) * NC + kg * 8;
        bf16x8 B0 = *(const bf16x8*)(xr);
        bf16x8 B1 = *(const bf16x8*)(xr + 32);
        f32x4 c0 = {0.f, 0.f, 0.f, 0.f}, c1 = {0.f, 0.f, 0.f, 0.f};
        c0 = __builtin_amdgcn_mfma_f32_16x16x32_bf16(A[0][0], B0, c0, 0, 0, 0);
        c0 = __builtin_amdgcn_mfma_f32_16x16x32_bf16(A[0][1], B1, c0, 0, 0, 0);
        c1 = __builtin_amdgcn_mfma_f32_16x16x32_bf16(A[1][0], B0, c1, 0, 0, 0);
        c1 = __builtin_amdgcn_mfma_f32_16x16x32_bf16(A[1][1], B1, c1, 0, 0, 0);
        float sp = 0.f;
#pragma unroll
        for (int r = 0; r < 4; ++r) {
            sp = fmaf(ax0[r], fmaxf(c0[r], 0.f), sp);
            sp = fmaf(ax1[r], fmaxf(c1[r], 0.f), sp);
        }
        sp += __shfl_xor(sp, 16, 64);     // reduce over kg
        sp += __shfl_xor(sp, 32, 64);
        acc += 1.f / (1.f + __expf(-sp)); // every pixel counted 4x (kg copies)
    }
    acc = wave_sum64(acc) * 0.25f;
    if (lane == 0) atomicAdd(&red, acc);
    __syncthreads();
    if (threadIdx.x == 0) atomicAdd(&ws[O_SCA + b], red);
}

// p5: SK gating (fused) then out = K[b,o] + relu(wres x) via SWAPPED MFMA:
// D[px][o] -> each lane's 4 regs are 4 consecutive n -> float4 stores.
__global__ __launch_bounds__(256) void k_p5(
    const unsigned short* __restrict__ xt, const float* __restrict__ ws,
    const float* __restrict__ wsk1, const float* __restrict__ wsk2,
    float* __restrict__ out) {
    const int b = blockIdx.y;
    const int tid = threadIdx.x;
    const int lane = tid & 63;
    const int wid = blockIdx.x * 4 + (tid >> 6);
    const int col = lane & 15, kg = lane >> 4;
    const unsigned short* af5 = (const unsigned short*)((const char*)ws + AF5_OFF);

    __shared__ float u_s[NC];
    __shared__ float a1_s[NCH];
    __shared__ float K_s[NC];

    // ---- fused pass4 (redundant per block) ----
    const float invn = 1.f / (float)NPIX;
    if (tid < NC) {
        float sca = ws[O_SCA + b];
        float sa = ws[O_SA + b * NC + tid];
        u_s[tid] = fmaf(sa, sca * invn, invn);
    }
    __syncthreads();
    if (tid < NCH) {
        float s = 0.f;
#pragma unroll
        for (int c = 0; c < NC; ++c) s = fmaf(wsk1[tid * NC + c], u_s[c], s);
        a1_s[tid] = fmaxf(s, 0.f);
    }
    __syncthreads();
    if (tid < NC) {
        float s2 = 0.f;
#pragma unroll
        for (int ch = 0; ch < NCH; ++ch) s2 = fmaf(wsk2[tid * NCH + ch], a1_s[ch], s2);
        s2 = fmaxf(s2, 0.f);
        float mx = s2;
#pragma unroll
        for (int m = 32; m; m >>= 1) mx = fmaxf(mx, __shfl_xor(mx, m, 64));
        float e = __expf(s2 - mx);
        float sm = e;
#pragma unroll
        for (int m = 32; m; m >>= 1) sm += __shfl_xor(sm, m, 64);
        float a = e / sm;
        float sca = ws[O_SCA + b];
        float sa = ws[O_SA + b * NC + tid];
        K_s[tid] = fmaf(a, sa * sca, 1.f - a);
    }
    __syncthreads();

    bf16x8 A[4][2];
#pragma unroll
    for (int t = 0; t < 4; ++t)
#pragma unroll
        for (int s = 0; s < 2; ++s)
            A[t][s] = *(const bf16x8*)(af5 + ((t * 2 + s) * 64 + lane) * 8);
    float kvc[4];
#pragma unroll
    for (int t = 0; t < 4; ++t) kvc[t] = K_s[t * 16 + col];

    for (int it = 0; it < TPW; ++it) {
        const int n0 = (wid * TPW + it) * 16;
        const unsigned short* xr = xt + ((size_t)b * NPIX + n0 + col) * NC + kg * 8;
        bf16x8 B0 = *(const bf16x8*)(xr);
        bf16x8 B1 = *(const bf16x8*)(xr + 32);
#pragma unroll
        for (int t = 0; t < 4; ++t) {
            f32x4 cc = {0.f, 0.f, 0.f, 0.f};
            cc = __builtin_amdgcn_mfma_f32_16x16x32_bf16(B0, A[t][0], cc, 0, 0, 0);
            cc = __builtin_amdgcn_mfma_f32_16x16x32_bf16(B1, A[t][1], cc, 0, 0, 0);
            float4 r;
            r.x = kvc[t] + fmaxf(cc[0], 0.f);
            r.y = kvc[t] + fmaxf(cc[1], 0.f);
            r.z = kvc[t] + fmaxf(cc[2], 0.f);
            r.w = kvc[t] + fmaxf(cc[3], 0.f);
            *(float4*)(out + ((size_t)(b * NC + t * 16 + col)) * NPIX + n0 + kg * 4) = r;
        }
    }
}

// ================= shared small kernel (p2) =================
__global__ __launch_bounds__(256) void k_pass2(
    const float* __restrict__ wup, float* __restrict__ ws) {
    const int b = threadIdx.x >> 6;
    const int lane = threadIdx.x & 63;
    __shared__ float ln_s[NB][NCH];
    float se = ws[O_SUME + b];
    float ctx = (lane < NCH) ? (ws[O_CTX + b * NCH + lane] / se) : 0.f;
    float v = ctx, v2 = ctx * ctx;
#pragma unroll
    for (int m = 16; m; m >>= 1) { v += __shfl_xor(v, m, 64); v2 += __shfl_xor(v2, m, 64); }
    float mu = v / (float)NCH;
    float var = v2 / (float)NCH - mu * mu;
    float lnv = (ctx - mu) * rsqrtf(var + 1e-5f);
    if (lane < NCH) ln_s[b][lane] = lnv;
    __syncthreads();
    float s = 0.f;
#pragma unroll
    for (int ch = 0; ch < NCH; ++ch) s = fmaf(wup[lane * NCH + ch], ln_s[b][ch], s);
    ws[O_SA + b * NC + lane] = fminf(fmaxf((s + 3.f) * (1.f / 6.f), 0.f), 1.f);
    if (lane < NCH) {
        float l = ws[O_QL + b * NCH + lane] * (1.f / (float)NPIX);
        float mx = l;
#pragma unroll
        for (int m = 16; m; m >>= 1) mx = fmaxf(mx, __shfl_xor(mx, m, 64));
        float e = __expf(l - mx);
        float sm = e;
#pragma unroll
        for (int m = 16; m; m >>= 1) sm += __shfl_xor(sm, m, 64);
        ws[O_AVGX + b * NCH + lane] = e / sm;
    }
}

// ================= FALLBACK PATH (R2, passing) =================
__global__ __launch_bounds__(256) void k_prep(
    const float* __restrict__ wqr, const float* __restrict__ wvr,
    const float* __restrict__ wql, const float* __restrict__ wvl,
    const float* __restrict__ wres, float* __restrict__ ws) {
    for (int i = threadIdx.x; i < NC * WT1_S; i += 256) {
        int c = i / WT1_S, j = i % WT1_S;
        float v = 0.f;
        if (j == 0)       v = wqr[c];
        else if (j <= 32) v = wvr[(j - 1) * NC + c];
        else if (j <= 64) v = wql[(j - 33) * NC + c];
        ws[O_WT1 + i] = v;
    }
    for (int i = threadIdx.x; i < NC * NCH; i += 256) {
        int c = i / NCH, ch = i % NCH;
        ws[O_WT3 + i] = wvl[ch * NC + c];
    }
    for (int i = threadIdx.x; i < NC * NC; i += 256) {
        int c = i / NC, o = i % NC;
        ws[O_WT5 + i] = wres[o * NC + c];
    }
}

__global__ __launch_bounds__(256) void k_pass1(
    const float* __restrict__ x, float* __restrict__ ws) {
    const int b = blockIdx.y;
    const float* xb = x + (size_t)b * NC * NPIX;
    __shared__ float wlds[NC * WT1_S];
    __shared__ float red[1 + 2 * NCH];
    for (int i = threadIdx.x; i < NC * WT1_S; i += 256) wlds[i] = ws[O_WT1 + i];
    for (int i = threadIdx.x; i < 1 + 2 * NCH; i += 256) red[i] = 0.f;
    __syncthreads();
    const int n2 = blockIdx.x * 256 + threadIdx.x;
    float dqr0 = 0.f, dqr1 = 0.f;
    float dv[NCH][2], dq[NCH][2];
#pragma unroll
    for (int i = 0; i < NCH; ++i) { dv[i][0] = dv[i][1] = 0.f; dq[i][0] = dq[i][1] = 0.f; }
    for (int c = 0; c < NC; ++c) {
        const float2 xv = *(const float2*)(xb + (size_t)c * NPIX + 2 * n2);
        const float* wr = wlds + c * WT1_S;
        dqr0 = fmaf(wr[0], xv.x, dqr0);
        dqr1 = fmaf(wr[0], xv.y, dqr1);
#pragma unroll
        for (int ch = 0; ch < NCH; ++ch) {
            const float wv = wr[1 + ch], wq = wr[33 + ch];
            dv[ch][0] = fmaf(wv, xv.x, dv[ch][0]);
            dv[ch][1] = fmaf(wv, xv.y, dv[ch][1]);
            dq[ch][0] = fmaf(wq, xv.x, dq[ch][0]);
            dq[ch][1] = fmaf(wq, xv.y, dq[ch][1]);
        }
    }
    const float e0 = __expf(fmaxf(dqr0, 0.f));
    const float e1 = __expf(fmaxf(dqr1, 0.f));
    float acc_e = wave_sum64(e0 + e1);
    if ((threadIdx.x & 63) == 0) atomicAdd(&red[0], acc_e);
#pragma unroll
    for (int ch = 0; ch < NCH; ++ch) {
        float v = wave_sum64(fmaxf(dv[ch][0], 0.f) * e0 + fmaxf(dv[ch][1], 0.f) * e1);
        float q = wave_sum64(fmaxf(dq[ch][0], 0.f) + fmaxf(dq[ch][1], 0.f));
        if ((threadIdx.x & 63) == 0) { atomicAdd(&red[1 + ch], v); atomicAdd(&red[1 + NCH + ch], q); }
    }
    __syncthreads();
    if (threadIdx.x == 0) atomicAdd(&ws[O_SUME + b], red[0]);
    if (threadIdx.x < NCH) {
        atomicAdd(&ws[O_CTX + b * NCH + threadIdx.x], red[1 + threadIdx.x]);
        atomicAdd(&ws[O_QL  + b * NCH + threadIdx.x], red[1 + NCH + threadIdx.x]);
    }
}

__global__ __launch_bounds__(256) void k_pass3(
    const float* __restrict__ x, float* __restrict__ ws) {
    const int b = blockIdx.y;
    const float* xb = x + (size_t)b * NC * NPIX;
    __shared__ float wlds[NC * NCH];
    __shared__ float red;
    for (int i = threadIdx.x; i < NC * NCH; i += 256) wlds[i] = ws[O_WT3 + i];
    if (threadIdx.x == 0) red = 0.f;
    __syncthreads();
    const int n2 = blockIdx.x * 256 + threadIdx.x;
    float dv[NCH][2];
#pragma unroll
    for (int i = 0; i < NCH; ++i) dv[i][0] = dv[i][1] = 0.f;
    for (int c = 0; c < NC; ++c) {
        const float2 xv = *(const float2*)(xb + (size_t)c * NPIX + 2 * n2);
        const float* wr = wlds + c * NCH;
#pragma unroll
        for (int ch = 0; ch < NCH; ++ch) {
            dv[ch][0] = fmaf(wr[ch], xv.x, dv[ch][0]);
            dv[ch][1] = fmaf(wr[ch], xv.y, dv[ch][1]);
        }
    }
    float s0 = 0.f, s1 = 0.f;
#pragma unroll
    for (int ch = 0; ch < NCH; ++ch) {
        const float ax = ws[O_AVGX + b * NCH + ch];
        s0 = fmaf(ax, fmaxf(dv[ch][0], 0.f), s0);
        s1 = fmaf(ax, fmaxf(dv[ch][1], 0.f), s1);
    }
    float acc = wave_sum64(1.f / (1.f + __expf(-s0)) + 1.f / (1.f + __expf(-s1)));
    if ((threadIdx.x & 63) == 0) atomicAdd(&red, acc);
    __syncthreads();
    if (threadIdx.x == 0) atomicAdd(&ws[O_SCA + b], red);
}

__global__ __launch_bounds__(256) void k_pass4(
    const float* __restrict__ wsk1, const float* __restrict__ wsk2,
    float* __restrict__ ws) {
    const int b = threadIdx.x >> 6;
    const int lane = threadIdx.x & 63;
    __shared__ float u_s[NB][NC];
    __shared__ float a1_s[NB][NCH];
    float sca = ws[O_SCA + b];
    float sa = ws[O_SA + b * NC + lane];
    float invn = 1.f / (float)NPIX;
    u_s[b][lane] = fmaf(sa, sca * invn, invn);
    __syncthreads();
    if (lane < NCH) {
        float s = 0.f;
#pragma unroll
        for (int c = 0; c < NC; ++c) s = fmaf(wsk1[lane * NC + c], u_s[b][c], s);
        a1_s[b][lane] = fmaxf(s, 0.f);
    }
    __syncthreads();
    float s2 = 0.f;
#pragma unroll
    for (int ch = 0; ch < NCH; ++ch) s2 = fmaf(wsk2[lane * NCH + ch], a1_s[b][ch], s2);
    s2 = fmaxf(s2, 0.f);
    float mx = s2;
#pragma unroll
    for (int m = 32; m; m >>= 1) mx = fmaxf(mx, __shfl_xor(mx, m, 64));
    float e = __expf(s2 - mx);
    float sm = e;
#pragma unroll
    for (int m = 32; m; m >>= 1) sm += __shfl_xor(sm, m, 64);
    float a = e / sm;
    ws[O_K + b * NC + lane] = fmaf(a, sa * sca, 1.f - a);
}

__global__ __launch_bounds__(256) void k_pass5(
    const float* __restrict__ x, const float* __restrict__ ws,
    float* __restrict__ out) {
    const int b = blockIdx.y;
    const float* xb = x + (size_t)b * NC * NPIX;
    float* ob = out + (size_t)b * NC * NPIX;
    __shared__ float wlds[NC * NC];
    for (int i = threadIdx.x; i < NC * NC; i += 256) wlds[i] = ws[O_WT5 + i];
    __syncthreads();
    const int n2 = blockIdx.x * 256 + threadIdx.x;
    float acc[NC][2];
#pragma unroll
    for (int o = 0; o < NC; ++o) acc[o][0] = acc[o][1] = 0.f;
    for (int c = 0; c < NC; ++c) {
        const float2 xv = *(const float2*)(xb + (size_t)c * NPIX + 2 * n2);
        const float* wr = wlds + c * NC;
#pragma unroll
        for (int o = 0; o < NC; ++o) {
            acc[o][0] = fmaf(wr[o], xv.x, acc[o][0]);
            acc[o][1] = fmaf(wr[o], xv.y, acc[o][1]);
        }
    }
#pragma unroll
    for (int o = 0; o < NC; ++o) {
        const float k = ws[O_K + b * NC + o];
        float2 r;
        r.x = k + fmaxf(acc[o][0], 0.f);
        r.y = k + fmaxf(acc[o][1], 0.f);
        *(float2*)(ob + (size_t)o * NPIX + 2 * n2) = r;
    }
}

extern "C" void kernel_launch(void* const* d_in, const int* in_sizes, int n_in,
                              void* d_out, int out_size, void* d_ws, size_t ws_size,
                              hipStream_t stream) {
    const float* x    = (const float*)d_in[0];
    const float* wqr  = (const float*)d_in[1];
    const float* wvr  = (const float*)d_in[2];
    const float* wup  = (const float*)d_in[3];
    const float* wql  = (const float*)d_in[4];
    const float* wvl  = (const float*)d_in[5];
    const float* wsk1 = (const float*)d_in[6];
    const float* wsk2 = (const float*)d_in[7];
    const float* wres = (const float*)d_in[8];
    float* out = (float*)d_out;
    float* ws  = (float*)d_ws;

    dim3 blk(256);

    if (ws_size >= (size_t)WS_NEED) {
        unsigned short* xt = (unsigned short*)((char*)d_ws + XT_OFF);
        k_prepf<<<dim3(1), blk, 0, stream>>>(wqr, wvr, wql, wvl, wres, ws);
        k_Tp1<<<dim3(NPBLK, NB), blk, 0, stream>>>(x, xt, ws, ws);
        k_red<<<dim3(65, NB), blk, 0, stream>>>(ws);
        k_pass2<<<dim3(1), blk, 0, stream>>>(wup, ws);
        k_p3v<<<dim3(NPIX / (16 * 4 * TPW), NB), blk, 0, stream>>>(xt, ws);
        k_p5<<<dim3(NPIX / (16 * 4 * TPW), NB), blk, 0, stream>>>(xt, ws, wsk1, wsk2, out);
    } else {
        hipMemsetAsync(d_ws, 0, 272 * sizeof(float), stream);
        k_prep<<<dim3(1), blk, 0, stream>>>(wqr, wvr, wql, wvl, wres, ws);
        dim3 g(NPIX / (2 * 256), NB);
        k_pass1<<<g, blk, 0, stream>>>(x, ws);
        k_pass2<<<dim3(1), blk, 0, stream>>>(wup, ws);
        k_pass3<<<g, blk, 0, stream>>>(x, ws);
        k_pass4<<<dim3(1), blk, 0, stream>>>(wsk1, wsk2, ws);
        k_pass5<<<g, blk, 0, stream>>>(x, ws, out);
    }
}